// Round 1
// baseline (1264.445 us; speedup 1.0000x reference)
//
#include <hip/hip_runtime.h>
#include <math.h>

#define T_N     4096
#define LOG2N   12
#define B_N     64
#define C_N     64
#define NFILT   2
#define F_BINS  2049
#define NPAIRS  2016
#define NFEAT   4032
#define NOUT    4
#define CHUNK_B 8
#define NCHUNK  8
#define TSPLITS 8
#define TT      64

// ---- ws layout (float units) ----
#define OFF_FILT  0
#define FILT_FLOATS (4 * F_BINS)                       // Fre[2][2049], Fim[2][2049]
#define OFF_U     16384                                 // 8-byte aligned
#define U_FLOATS  (CHUNK_B * NFILT * C_N * T_N * 2)     // 8,388,608 (33.5 MB)
#define OFF_G     (OFF_U + U_FLOATS)
#define G_FLOATS  (B_N * NFILT * C_N * C_N * 2)         // 1,048,576 (4 MB)
#define OFF_FEATS (OFF_G + G_FLOATS)
#define OFF_STATS (OFF_FEATS + B_N * NFEAT)

#define PI_F 3.14159265358979323846f

// ---------------- filter construction (1 block) ----------------
// Stores filt_re/filt_im with dc_scale (1 at k=0 else 2) and 1/T folded in.
__global__ __launch_bounds__(256) void filter_kernel(
    const float* __restrict__ fm_, const float* __restrict__ bw_,
    const float* __restrict__ sp_, const float* __restrict__ gd_,
    float* __restrict__ filt) {
  __shared__ float smag[F_BINS];
  __shared__ float sred[256];
  const int tid = threadIdx.x;
  for (int f = 0; f < NFILT; ++f) {
    const float fm = fminf(fmaxf(fm_[f], 1.0f / 128.0f), 45.0f / 128.0f);
    const float bw = fminf(fmaxf(bw_[f], 1.0f / 128.0f), 1.0f);
    const float p  = fminf(fmaxf(sp_[f], 2.0f), 3.0f) * 8.0f - 14.0f;
    const float gd = gd_[f];
    const float scale = bw / (2.0f * powf(0.69314718055994531f, 1.0f / p));
    float lmax = 0.0f;
    for (int i = tid; i < F_BINS; i += 256) {
      const float n = (float)i / 2048.0f;
      const float m = expf(-powf((fabsf(n - fm) + 1e-8f) / scale, p));
      smag[i] = m;
      lmax = fmaxf(lmax, m);
    }
    sred[tid] = lmax;
    __syncthreads();
    for (int s = 128; s > 0; s >>= 1) {
      if (tid < s) sred[tid] = fmaxf(sred[tid], sred[tid + s]);
      __syncthreads();
    }
    const float inv = 1.0f / sred[0];
    __syncthreads();
    for (int i = tid; i < F_BINS; i += 256) {
      const float m = smag[i] * inv;
      const float pha = -gd * ((float)i * 0.125f) * PI_F;  // phase[i] = i/8
      float sn, cs;
      sincosf(pha, &sn, &cs);
      const float dcs = (i == 0) ? 1.0f : 2.0f;
      const float sT = dcs * (1.0f / (float)T_N);           // dc_scale * 1/T folded
      filt[f * F_BINS + i]              = m * cs * sT;
      filt[2 * F_BINS + f * F_BINS + i] = m * sn * sT;
    }
    __syncthreads();
  }
}

// ---------------- in-place radix-2 DIT FFT (input bit-reversed) ----------------
__device__ __forceinline__ void fft_inplace(float* sre, float* sim, float sign, int tid) {
  __syncthreads();
  for (int s = 0; s < LOG2N; ++s) {
    const int mh = 1 << s;
    const float astep = sign * PI_F / (float)mh;
    for (int t = tid; t < (T_N / 2); t += 256) {
      const int pos = t & (mh - 1);
      const int i0 = ((t >> s) << (s + 1)) + pos;
      const int i1 = i0 + mh;
      float sn, cs;
      sincosf(astep * (float)pos, &sn, &cs);
      const float br = sre[i1], bi = sim[i1];
      const float tr = br * cs - bi * sn;
      const float ti = br * sn + bi * cs;
      const float ar = sre[i0], ai = sim[i0];
      sre[i0] = ar + tr; sim[i0] = ai + ti;
      sre[i1] = ar - tr; sim[i1] = ai - ti;
    }
    __syncthreads();
  }
}

// ---------------- forward FFT + filter + inverse FFT + normalize ----------------
// one block per (chunk-local b, c); writes unit phasors u (float2) to ws
__global__ __launch_bounds__(256) void fftfilt_kernel(
    const float* __restrict__ x, const float* __restrict__ filt,
    float2* __restrict__ u, int chunk) {
  const int bb = blockIdx.x >> 6;   // / C_N
  const int c  = blockIdx.x & 63;
  const int b  = chunk * CHUNK_B + bb;
  const int tid = threadIdx.x;
  __shared__ float sre[T_N], sim[T_N];
  __shared__ float sxr[F_BINS], sxi[F_BINS];

  const float* xp = x + ((size_t)(b * C_N + c)) * T_N;
  for (int i = tid; i < T_N; i += 256) {
    const int r = __brev((unsigned)i) >> (32 - LOG2N);
    sre[r] = xp[i];
    sim[r] = 0.0f;
  }
  fft_inplace(sre, sim, -1.0f, tid);   // forward; output natural order

  for (int i = tid; i < F_BINS; i += 256) { sxr[i] = sre[i]; sxi[i] = sim[i]; }
  __syncthreads();

  for (int f = 0; f < NFILT; ++f) {
    const float* Fre = filt + f * F_BINS;
    const float* Fim = filt + 2 * F_BINS + f * F_BINS;
    for (int i = tid; i < T_N; i += 256) {
      const int r = __brev((unsigned)i) >> (32 - LOG2N);
      float zr = 0.0f, zi = 0.0f;
      if (i < F_BINS) {
        zr = sxr[i] * Fre[i];   // component-wise: Xre*filt_re
        zi = sxi[i] * Fim[i];   //                 Xim*filt_im
      }
      sre[r] = zr; sim[r] = zi;
    }
    fft_inplace(sre, sim, +1.0f, tid);  // inverse (1/T folded into filt)

    float2* up = u + (((size_t)(bb * NFILT + f)) * C_N + c) * T_N;
    for (int i = tid; i < T_N; i += 256) {
      const float ar = sre[i], ai = sim[i];
      const float amp = sqrtf(ar * ar + ai * ai + 1e-6f);
      up[i] = make_float2(ar / amp, ai / amp);
    }
    __syncthreads();
  }
}

// ---------------- pairwise complex gram: G[c][d] = sum_t u_c * conj(u_d) -----
// grid: (CHUNK_B*NFILT slices) x 3 channel-tile-pairs x TSPLITS t-splits
__global__ __launch_bounds__(256) void gram_kernel(
    const float2* __restrict__ u, float* __restrict__ G, int chunk) {
  const int bid = blockIdx.x;
  const int ts   = bid & (TSPLITS - 1);
  const int tile = (bid >> 3) % 3;          // 0:(0,0) 1:(0,1) 2:(1,1)
  const int sl   = bid / (3 * TSPLITS);     // 0..CHUNK_B*NFILT-1
  const int cg = (tile == 2) ? 1 : 0;
  const int dg = (tile == 0) ? 0 : 1;

  const float2* uc = u + ((size_t)(sl * C_N + cg * 32)) * T_N;
  const float2* ud = u + ((size_t)(sl * C_N + dg * 32)) * T_N;
  const int t0 = ts * (T_N / TSPLITS);

  __shared__ float2 sc[32][TT + 1], sd[32][TT + 1];
  const int tid = threadIdx.x;
  const int ty = tid >> 4, tx = tid & 15;

  float g00r = 0, g00i = 0, g01r = 0, g01i = 0;
  float g10r = 0, g10i = 0, g11r = 0, g11i = 0;

  for (int tc = 0; tc < T_N / TSPLITS; tc += TT) {
    for (int idx = tid; idx < 32 * TT; idx += 256) {
      const int ch = idx >> 6, tt = idx & (TT - 1);
      sc[ch][tt] = uc[(size_t)ch * T_N + t0 + tc + tt];
      sd[ch][tt] = ud[(size_t)ch * T_N + t0 + tc + tt];
    }
    __syncthreads();
#pragma unroll 8
    for (int tt = 0; tt < TT; ++tt) {
      const float2 a0 = sc[2 * ty][tt], a1 = sc[2 * ty + 1][tt];
      const float2 b0 = sd[2 * tx][tt], b1 = sd[2 * tx + 1][tt];
      g00r += a0.x * b0.x + a0.y * b0.y; g00i += a0.y * b0.x - a0.x * b0.y;
      g01r += a0.x * b1.x + a0.y * b1.y; g01i += a0.y * b1.x - a0.x * b1.y;
      g10r += a1.x * b0.x + a1.y * b0.y; g10i += a1.y * b0.x - a1.x * b0.y;
      g11r += a1.x * b1.x + a1.y * b1.y; g11i += a1.y * b1.x - a1.x * b1.y;
    }
    __syncthreads();
  }

  const int slice_g = chunk * (CHUNK_B * NFILT) + sl;
  float* Gp = G + (size_t)slice_g * (C_N * C_N * 2);
  const int R0 = cg * 32 + 2 * ty, Cc0 = dg * 32 + 2 * tx;
  atomicAdd(&Gp[(R0 * C_N + Cc0) * 2 + 0], g00r);
  atomicAdd(&Gp[(R0 * C_N + Cc0) * 2 + 1], g00i);
  atomicAdd(&Gp[(R0 * C_N + Cc0 + 1) * 2 + 0], g01r);
  atomicAdd(&Gp[(R0 * C_N + Cc0 + 1) * 2 + 1], g01i);
  atomicAdd(&Gp[((R0 + 1) * C_N + Cc0) * 2 + 0], g10r);
  atomicAdd(&Gp[((R0 + 1) * C_N + Cc0) * 2 + 1], g10i);
  atomicAdd(&Gp[((R0 + 1) * C_N + Cc0 + 1) * 2 + 0], g11r);
  atomicAdd(&Gp[((R0 + 1) * C_N + Cc0 + 1) * 2 + 1], g11i);
}

// ---------------- PLV + scatter to feature layout ----------------
__global__ __launch_bounds__(256) void plv_kernel(
    const float* __restrict__ G, float* __restrict__ feats) {
  const int idx = blockIdx.x * 256 + threadIdx.x;
  if (idx >= B_N * NFILT * NPAIRS) return;
  const int slice = idx / NPAIRS;
  const int p = idx - slice * NPAIRS;
  const int b = slice >> 1, f = slice & 1;
  int c = 0, rem = p;
  while (rem >= 63 - c) { rem -= 63 - c; ++c; }
  const int d = c + 1 + rem;
  const float* Gp = G + (size_t)slice * (C_N * C_N * 2) + (c * C_N + d) * 2;
  const float gr = Gp[0], gi = Gp[1];
  const float plv = sqrtf(gr * gr + gi * gi + 1e-6f) * (1.0f / (float)T_N);
  feats[b * NFEAT + p * NFILT + f] = plv;
}

// ---------------- batch stats (training-mode BN, biased var) ----------------
__global__ __launch_bounds__(256) void stats_kernel(
    const float* __restrict__ feats, float* __restrict__ stats) {
  const int j = blockIdx.x * 256 + threadIdx.x;
  if (j >= NFEAT) return;
  float s = 0.0f;
  for (int b = 0; b < B_N; ++b) s += feats[b * NFEAT + j];
  const float mu = s * (1.0f / (float)B_N);
  float v = 0.0f;
  for (int b = 0; b < B_N; ++b) {
    const float d = feats[b * NFEAT + j] - mu;
    v += d * d;
  }
  v *= (1.0f / (float)B_N);
  stats[j] = mu;
  stats[NFEAT + j] = 1.0f / sqrtf(v + 1e-5f);
}

// ---------------- normalize + linear ----------------
__global__ __launch_bounds__(256) void out_kernel(
    const float* __restrict__ feats, const float* __restrict__ stats,
    const float* __restrict__ w, const float* __restrict__ lb,
    float* __restrict__ out) {
  const int b = blockIdx.x;
  const int tid = threadIdx.x;
  float acc0 = 0, acc1 = 0, acc2 = 0, acc3 = 0;
  for (int j = tid; j < NFEAT; j += 256) {
    const float v = (feats[b * NFEAT + j] - stats[j]) * stats[NFEAT + j];
    acc0 += v * w[0 * NFEAT + j];
    acc1 += v * w[1 * NFEAT + j];
    acc2 += v * w[2 * NFEAT + j];
    acc3 += v * w[3 * NFEAT + j];
  }
  __shared__ float red[4][256];
  red[0][tid] = acc0; red[1][tid] = acc1; red[2][tid] = acc2; red[3][tid] = acc3;
  __syncthreads();
  for (int s = 128; s > 0; s >>= 1) {
    if (tid < s) {
#pragma unroll
      for (int o = 0; o < 4; ++o) red[o][tid] += red[o][tid + s];
    }
    __syncthreads();
  }
  if (tid < 4) out[b * NOUT + tid] = red[tid][0] + lb[tid];
}

extern "C" void kernel_launch(void* const* d_in, const int* in_sizes, int n_in,
                              void* d_out, int out_size, void* d_ws, size_t ws_size,
                              hipStream_t stream) {
  const float* x  = (const float*)d_in[0];
  const float* fm = (const float*)d_in[1];
  const float* bw = (const float*)d_in[2];
  const float* sp = (const float*)d_in[3];
  const float* gd = (const float*)d_in[4];
  const float* lw = (const float*)d_in[5];
  const float* lb = (const float*)d_in[6];
  float* out = (float*)d_out;
  float* W = (float*)d_ws;

  float*  filt  = W + OFF_FILT;
  float2* u     = (float2*)(W + OFF_U);
  float*  G     = W + OFF_G;
  float*  feats = W + OFF_FEATS;
  float*  stats = W + OFF_STATS;

  hipMemsetAsync(G, 0, (size_t)G_FLOATS * sizeof(float), stream);
  filter_kernel<<<1, 256, 0, stream>>>(fm, bw, sp, gd, filt);

  for (int chunk = 0; chunk < NCHUNK; ++chunk) {
    fftfilt_kernel<<<CHUNK_B * C_N, 256, 0, stream>>>(x, filt, u, chunk);
    gram_kernel<<<CHUNK_B * NFILT * 3 * TSPLITS, 256, 0, stream>>>(u, G, chunk);
  }

  plv_kernel<<<(B_N * NFILT * NPAIRS + 255) / 256, 256, 0, stream>>>(G, feats);
  stats_kernel<<<(NFEAT + 255) / 256, 256, 0, stream>>>(feats, stats);
  out_kernel<<<B_N, 256, 0, stream>>>(feats, stats, lw, lb, out);
}

// Round 2
// 302.759 us; speedup vs baseline: 4.1764x; 4.1764x over previous
//
#include <hip/hip_runtime.h>
#include <math.h>

#define T_N     4096
#define B_N     64
#define C_N     64
#define NFILT   2
#define F_BINS  2049
#define NPAIRS  2016
#define NFEAT   4032
#define NOUT    4
#define CHUNK_B 16
#define NCHUNK  4
#define TSG     8

#define PI_F 3.14159265358979323846f

typedef _Float16 f16x8 __attribute__((ext_vector_type(8)));
typedef _Float16 f16x2 __attribute__((ext_vector_type(2)));
typedef float    f32x4 __attribute__((ext_vector_type(4)));

// ---- ws layout (bytes) ----
#define FILT_BYTES  (2 * 2 * 4096 * 4)                    // 65536
#define UR_BYTES    (CHUNK_B * 2 * 64 * 4096 * 2)         // 16777216
#define G_BYTES     (128 * 3 * 4096 * 4)                  // 6291456
#define OFF_UR      65536
#define OFF_UI      (OFF_UR + UR_BYTES)
#define OFF_G       (OFF_UI + UR_BYTES)
#define OFF_FEATS   (OFF_G + G_BYTES)
#define OFF_STATS   (OFF_FEATS + B_N * NFEAT * 4)

__device__ __forceinline__ int rev4_12(int p) {
  int r = 0;
#pragma unroll
  for (int d = 0; d < 6; ++d) { r = (r << 2) | (p & 3); p >>= 2; }
  return r;
}

// ---------------- filter construction (1 block) ----------------
// Writes filters in base-4 digit-reversed order, with dc_scale and 1/T folded.
__global__ __launch_bounds__(256) void filter_kernel(
    const float* __restrict__ fm_, const float* __restrict__ bw_,
    const float* __restrict__ sp_, const float* __restrict__ gd_,
    float* __restrict__ filt) {
  __shared__ float smag[F_BINS];
  __shared__ float sred[256];
  const int tid = threadIdx.x;
  for (int f = 0; f < NFILT; ++f) {
    float* Fre = filt + f * 8192;
    float* Fim = Fre + 4096;
    for (int p = tid; p < 4096; p += 256) { Fre[p] = 0.0f; Fim[p] = 0.0f; }
    const float fm = fminf(fmaxf(fm_[f], 1.0f / 128.0f), 45.0f / 128.0f);
    const float bw = fminf(fmaxf(bw_[f], 1.0f / 128.0f), 1.0f);
    const float pp = fminf(fmaxf(sp_[f], 2.0f), 3.0f) * 8.0f - 14.0f;
    const float gd = gd_[f];
    const float scale = bw / (2.0f * powf(0.69314718055994531f, 1.0f / pp));
    float lmax = 0.0f;
    for (int i = tid; i < F_BINS; i += 256) {
      const float n = (float)i / 2048.0f;
      const float m = expf(-powf((fabsf(n - fm) + 1e-8f) / scale, pp));
      smag[i] = m;
      lmax = fmaxf(lmax, m);
    }
    sred[tid] = lmax;
    __syncthreads();
    for (int s = 128; s > 0; s >>= 1) {
      if (tid < s) sred[tid] = fmaxf(sred[tid], sred[tid + s]);
      __syncthreads();
    }
    const float inv = 1.0f / sred[0];
    __syncthreads();
    for (int k = tid; k < F_BINS; k += 256) {
      const float m = smag[k] * inv;
      const float pha = -gd * ((float)k * 0.125f) * PI_F;
      float sn, cs;
      sincosf(pha, &sn, &cs);
      const float dcs = (k == 0) ? 1.0f : 2.0f;
      const float sT = dcs * (1.0f / (float)T_N);
      const int p = rev4_12(k);           // involution: position holding bin k
      Fre[p] = m * cs * sT;
      Fim[p] = m * sn * sT;
    }
    __syncthreads();
  }
}

// ---------------- radix-4 DIF forward: natural in -> digit-reversed out ------
__device__ __forceinline__ void r4_fwd(float* __restrict__ sre,
                                       float* __restrict__ sim, int tid) {
  for (int m = 1024; m >= 4; m >>= 2) {
    __syncthreads();
    const float astep = -PI_F / (2.0f * (float)m);
#pragma unroll 4
    for (int t = tid; t < 1024; t += 256) {
      const int j = t & (m - 1);
      const int base = ((t - j) << 2) + j;
      float ar = sre[base],         ai = sim[base];
      float br = sre[base + m],     bi = sim[base + m];
      float cr = sre[base + 2 * m], ci = sim[base + 2 * m];
      float dr = sre[base + 3 * m], di = sim[base + 3 * m];
      const float t0r = ar + cr, t0i = ai + ci;
      const float t1r = ar - cr, t1i = ai - ci;
      const float t2r = br + dr, t2i = bi + di;
      const float t3r = br - dr, t3i = bi - di;
      const float ang = astep * (float)j;
      const float c1 = __cosf(ang), s1 = __sinf(ang);
      const float c2 = c1 * c1 - s1 * s1, s2 = 2.0f * c1 * s1;
      const float c3 = c2 * c1 - s2 * s1, s3 = c2 * s1 + s2 * c1;
      sre[base] = t0r + t2r; sim[base] = t0i + t2i;
      float yr = t1r + t3i, yi = t1i - t3r;              // (t1 - i t3) * W^j
      sre[base + m] = yr * c1 - yi * s1; sim[base + m] = yr * s1 + yi * c1;
      yr = t0r - t2r; yi = t0i - t2i;                    // (t0 - t2) * W^2j
      sre[base + 2 * m] = yr * c2 - yi * s2; sim[base + 2 * m] = yr * s2 + yi * c2;
      yr = t1r - t3i; yi = t1i + t3r;                    // (t1 + i t3) * W^3j
      sre[base + 3 * m] = yr * c3 - yi * s3; sim[base + 3 * m] = yr * s3 + yi * c3;
    }
  }
  __syncthreads();                                       // m = 1, W = 1, vectorized
#pragma unroll 4
  for (int t = tid; t < 1024; t += 256) {
    const int base = t << 2;
    float4 re = *(float4*)&sre[base];
    float4 im = *(float4*)&sim[base];
    const float t0r = re.x + re.z, t0i = im.x + im.z;
    const float t1r = re.x - re.z, t1i = im.x - im.z;
    const float t2r = re.y + re.w, t2i = im.y + im.w;
    const float t3r = re.y - re.w, t3i = im.y - im.w;
    re.x = t0r + t2r; im.x = t0i + t2i;
    re.y = t1r + t3i; im.y = t1i - t3r;
    re.z = t0r - t2r; im.z = t0i - t2i;
    re.w = t1r - t3i; im.w = t1i + t3r;
    *(float4*)&sre[base] = re;
    *(float4*)&sim[base] = im;
  }
}

// ---------------- radix-4 DIT inverse: digit-reversed in -> natural out ------
// Unscaled conj-DFT; overall x4096 cancelled by 1/T folded into the filter.
__device__ __forceinline__ void r4_inv(float* __restrict__ sre,
                                       float* __restrict__ sim, int tid) {
  __syncthreads();                                       // m = 1, V = 1, vectorized
#pragma unroll 4
  for (int t = tid; t < 1024; t += 256) {
    const int base = t << 2;
    float4 re = *(float4*)&sre[base];
    float4 im = *(float4*)&sim[base];
    const float t0r = re.x + re.z, t0i = im.x + im.z;
    const float t1r = re.x - re.z, t1i = im.x - im.z;
    const float t2r = re.y + re.w, t2i = im.y + im.w;
    const float t3r = re.y - re.w, t3i = im.y - im.w;
    re.x = t0r + t2r; im.x = t0i + t2i;
    re.y = t1r - t3i; im.y = t1i + t3r;                  // t1 + i t3
    re.z = t0r - t2r; im.z = t0i - t2i;
    re.w = t1r + t3i; im.w = t1i - t3r;                  // t1 - i t3
    *(float4*)&sre[base] = re;
    *(float4*)&sim[base] = im;
  }
  for (int m = 4; m <= 1024; m <<= 2) {
    __syncthreads();
    const float astep = PI_F / (2.0f * (float)m);
#pragma unroll 4
    for (int t = tid; t < 1024; t += 256) {
      const int j = t & (m - 1);
      const int base = ((t - j) << 2) + j;
      const float ang = astep * (float)j;
      const float c1 = __cosf(ang), s1 = __sinf(ang);
      const float c2 = c1 * c1 - s1 * s1, s2 = 2.0f * c1 * s1;
      const float c3 = c2 * c1 - s2 * s1, s3 = c2 * s1 + s2 * c1;
      const float b0r = sre[base], b0i = sim[base];
      float yr = sre[base + m], yi = sim[base + m];
      const float b1r = yr * c1 - yi * s1, b1i = yr * s1 + yi * c1;
      yr = sre[base + 2 * m]; yi = sim[base + 2 * m];
      const float b2r = yr * c2 - yi * s2, b2i = yr * s2 + yi * c2;
      yr = sre[base + 3 * m]; yi = sim[base + 3 * m];
      const float b3r = yr * c3 - yi * s3, b3i = yr * s3 + yi * c3;
      const float t0r = b0r + b2r, t0i = b0i + b2i;
      const float t1r = b0r - b2r, t1i = b0i - b2i;
      const float t2r = b1r + b3r, t2i = b1i + b3i;
      const float t3r = b1r - b3r, t3i = b1i - b3i;
      sre[base] = t0r + t2r;         sim[base] = t0i + t2i;
      sre[base + m] = t1r - t3i;     sim[base + m] = t1i + t3r;
      sre[base + 2 * m] = t0r - t2r; sim[base + 2 * m] = t0i - t2i;
      sre[base + 3 * m] = t1r + t3i; sim[base + 3 * m] = t1i - t3r;
    }
  }
}

// ---------------- forward FFT + filter + inverse FFT + normalize -> f16 ------
__global__ __launch_bounds__(256) void fftfilt_kernel(
    const float* __restrict__ x, const float* __restrict__ filt,
    _Float16* __restrict__ Urg, _Float16* __restrict__ Uig, int chunk) {
  const int bb = blockIdx.x >> 6;
  const int c  = blockIdx.x & 63;
  const int b  = chunk * CHUNK_B + bb;
  const int tid = threadIdx.x;
  __shared__ float sre[T_N], sim[T_N];

  const float4* xv = (const float4*)(x + ((size_t)(b * C_N + c)) * T_N);
#pragma unroll
  for (int q = 0; q < 4; ++q) {
    const int i = q * 256 + tid;
    *(float4*)&sre[i * 4] = xv[i];
    *(float4*)&sim[i * 4] = make_float4(0.f, 0.f, 0.f, 0.f);
  }

  r4_fwd(sre, sim, tid);
  __syncthreads();

  float Xre[16], Xim[16];
#pragma unroll
  for (int q = 0; q < 16; ++q) {
    const int p = q * 256 + tid;
    Xre[q] = sre[p];
    Xim[q] = sim[p];
  }
  // no sync needed: each thread only overwrites the slots it itself read

#pragma unroll 1
  for (int f = 0; f < NFILT; ++f) {
    const float* Fre = filt + f * 8192;
    const float* Fim = Fre + 4096;
#pragma unroll
    for (int q = 0; q < 16; ++q) {
      const int p = q * 256 + tid;
      sre[p] = Xre[q] * Fre[p];   // component-wise: Xre*filt_re (digit-rev order)
      sim[p] = Xim[q] * Fim[p];
    }
    r4_inv(sre, sim, tid);
    __syncthreads();

    const int sl = bb * 2 + f;
    _Float16* upr = Urg + ((size_t)sl * C_N + c) * T_N;
    _Float16* upi = Uig + ((size_t)sl * C_N + c) * T_N;
#pragma unroll
    for (int q = 0; q < 8; ++q) {
      const int idx = q * 512 + tid * 2;
      const float2 ar = *(float2*)&sre[idx];
      const float2 ai = *(float2*)&sim[idx];
      const float i0 = rsqrtf(ar.x * ar.x + ai.x * ai.x + 1e-6f);
      const float i1 = rsqrtf(ar.y * ar.y + ai.y * ai.y + 1e-6f);
      f16x2 hr, hi;
      hr[0] = (_Float16)(ar.x * i0); hr[1] = (_Float16)(ar.y * i1);
      hi[0] = (_Float16)(ai.x * i0); hi[1] = (_Float16)(ai.y * i1);
      *(f16x2*)&upr[idx] = hr;
      *(f16x2*)&upi[idx] = hi;
    }
    __syncthreads();
  }
}

// ---------------- gram via f16 MFMA: Rr=UrUr^T, Ii=UiUi^T, Ri=UrUi^T ---------
__global__ __launch_bounds__(256) void gram_kernel(
    const _Float16* __restrict__ Urg, const _Float16* __restrict__ Uig,
    float* __restrict__ G, int chunk) {
  const int sl = blockIdx.x >> 3;
  const int ts = blockIdx.x & 7;
  const int tid = threadIdx.x;
  const int w = tid >> 6;
  const int lane = tid & 63;
  __shared__ _Float16 sUr[64 * 40], sUi[64 * 40];   // row stride 40 f16 = 80 B

  const int row = tid >> 2, quarter = tid & 3;
  const size_t goff = (size_t)sl * C_N * T_N + (size_t)row * T_N + ts * 512 + quarter * 8;
  const int loff = row * 40 + quarter * 8;
  const int frow = (lane & 15) * 40 + (lane >> 4) * 8;
  const int aoff = w * 640 + frow;

  f32x4 accRr[4] = {}, accIi[4] = {}, accRi[4] = {};

  for (int ks = 0; ks < 16; ++ks) {
    __syncthreads();
    *(f16x8*)&sUr[loff] = *(const f16x8*)&Urg[goff + ks * 32];
    *(f16x8*)&sUi[loff] = *(const f16x8*)&Uig[goff + ks * 32];
    __syncthreads();
    const f16x8 ar = *(const f16x8*)&sUr[aoff];
    const f16x8 ai = *(const f16x8*)&sUi[aoff];
#pragma unroll
    for (int n = 0; n < 4; ++n) {
      const f16x8 br = *(const f16x8*)&sUr[n * 640 + frow];
      const f16x8 bi = *(const f16x8*)&sUi[n * 640 + frow];
      accRr[n] = __builtin_amdgcn_mfma_f32_16x16x32_f16(ar, br, accRr[n], 0, 0, 0);
      accIi[n] = __builtin_amdgcn_mfma_f32_16x16x32_f16(ai, bi, accIi[n], 0, 0, 0);
      accRi[n] = __builtin_amdgcn_mfma_f32_16x16x32_f16(ar, bi, accRi[n], 0, 0, 0);
    }
  }

  const int gsl = chunk * (CHUNK_B * 2) + sl;
  float* Gs = G + (size_t)gsl * 12288;
  const int r0 = w * 16 + (lane >> 4) * 4;
  const int c0 = lane & 15;
#pragma unroll
  for (int n = 0; n < 4; ++n) {
#pragma unroll
    for (int e = 0; e < 4; ++e) {
      const int idx = (r0 + e) * 64 + n * 16 + c0;
      atomicAdd(&Gs[idx], accRr[n][e]);
      atomicAdd(&Gs[4096 + idx], accIi[n][e]);
      atomicAdd(&Gs[8192 + idx], accRi[n][e]);
    }
  }
}

// ---------------- PLV + scatter to feature layout ----------------
__global__ __launch_bounds__(256) void plv_kernel(
    const float* __restrict__ G, float* __restrict__ feats) {
  const int idx = blockIdx.x * 256 + threadIdx.x;
  if (idx >= B_N * NFILT * NPAIRS) return;
  const int slice = idx / NPAIRS;
  const int p = idx - slice * NPAIRS;
  const int b = slice >> 1, f = slice & 1;
  int c = 0, rem = p;
  while (rem >= 63 - c) { rem -= 63 - c; ++c; }
  const int d = c + 1 + rem;
  const float* Gs = G + (size_t)slice * 12288;
  const float cre = Gs[c * 64 + d] + Gs[4096 + c * 64 + d];        // rr + ii
  const float cim = Gs[8192 + c * 64 + d] - Gs[8192 + d * 64 + c]; // ri - ir
  const float plv = sqrtf(cre * cre + cim * cim + 1e-6f) * (1.0f / (float)T_N);
  feats[b * NFEAT + p * NFILT + f] = plv;
}

// ---------------- batch stats (training-mode BN, biased var) ----------------
__global__ __launch_bounds__(256) void stats_kernel(
    const float* __restrict__ feats, float* __restrict__ stats) {
  const int j = blockIdx.x * 256 + threadIdx.x;
  if (j >= NFEAT) return;
  float s = 0.0f;
  for (int b = 0; b < B_N; ++b) s += feats[b * NFEAT + j];
  const float mu = s * (1.0f / (float)B_N);
  float v = 0.0f;
  for (int b = 0; b < B_N; ++b) {
    const float d = feats[b * NFEAT + j] - mu;
    v += d * d;
  }
  v *= (1.0f / (float)B_N);
  stats[j] = mu;
  stats[NFEAT + j] = 1.0f / sqrtf(v + 1e-5f);
}

// ---------------- normalize + linear ----------------
__global__ __launch_bounds__(256) void out_kernel(
    const float* __restrict__ feats, const float* __restrict__ stats,
    const float* __restrict__ w, const float* __restrict__ lb,
    float* __restrict__ out) {
  const int b = blockIdx.x;
  const int tid = threadIdx.x;
  float acc0 = 0, acc1 = 0, acc2 = 0, acc3 = 0;
  for (int j = tid; j < NFEAT; j += 256) {
    const float v = (feats[b * NFEAT + j] - stats[j]) * stats[NFEAT + j];
    acc0 += v * w[0 * NFEAT + j];
    acc1 += v * w[1 * NFEAT + j];
    acc2 += v * w[2 * NFEAT + j];
    acc3 += v * w[3 * NFEAT + j];
  }
  __shared__ float red[4][256];
  red[0][tid] = acc0; red[1][tid] = acc1; red[2][tid] = acc2; red[3][tid] = acc3;
  __syncthreads();
  for (int s = 128; s > 0; s >>= 1) {
    if (tid < s) {
#pragma unroll
      for (int o = 0; o < 4; ++o) red[o][tid] += red[o][tid + s];
    }
    __syncthreads();
  }
  if (tid < 4) out[b * NOUT + tid] = red[tid][0] + lb[tid];
}

extern "C" void kernel_launch(void* const* d_in, const int* in_sizes, int n_in,
                              void* d_out, int out_size, void* d_ws, size_t ws_size,
                              hipStream_t stream) {
  const float* x  = (const float*)d_in[0];
  const float* fm = (const float*)d_in[1];
  const float* bw = (const float*)d_in[2];
  const float* sp = (const float*)d_in[3];
  const float* gd = (const float*)d_in[4];
  const float* lw = (const float*)d_in[5];
  const float* lb = (const float*)d_in[6];
  float* out = (float*)d_out;
  char* base = (char*)d_ws;

  float*    filt  = (float*)base;
  _Float16* Urg   = (_Float16*)(base + OFF_UR);
  _Float16* Uig   = (_Float16*)(base + OFF_UI);
  float*    G     = (float*)(base + OFF_G);
  float*    feats = (float*)(base + OFF_FEATS);
  float*    stats = (float*)(base + OFF_STATS);

  hipMemsetAsync(G, 0, G_BYTES, stream);
  filter_kernel<<<1, 256, 0, stream>>>(fm, bw, sp, gd, filt);

  for (int chunk = 0; chunk < NCHUNK; ++chunk) {
    fftfilt_kernel<<<CHUNK_B * C_N, 256, 0, stream>>>(x, filt, Urg, Uig, chunk);
    gram_kernel<<<CHUNK_B * 2 * TSG, 256, 0, stream>>>(Urg, Uig, G, chunk);
  }

  plv_kernel<<<(B_N * NFILT * NPAIRS + 255) / 256, 256, 0, stream>>>(G, feats);
  stats_kernel<<<(NFEAT + 255) / 256, 256, 0, stream>>>(feats, stats);
  out_kernel<<<B_N, 256, 0, stream>>>(feats, stats, lw, lb, out);
}

// Round 3
// 221.982 us; speedup vs baseline: 5.6962x; 1.3639x over previous
//
#include <hip/hip_runtime.h>
#include <math.h>

#define T_N     4096
#define B_N     64
#define C_N     64
#define NFILT   2
#define F_BINS  2049
#define NPAIRS  2016
#define NFEAT   4032
#define NOUT    4
#define TSG     4
#define NKS     32            // (4096/TSG)/32 K-steps per gram block

#define PI_F 3.14159265358979323846f

// LDS bank swizzle: fold addr bits 5-7 into bank bits 2-4. Makes every FFT
// stage stride {1,4,16,64,256,1024} <=2-way (free on wave64).
#define SWZ(a) ((a) ^ (((a) >> 3) & 28))

typedef _Float16 f16x8 __attribute__((ext_vector_type(8)));
typedef _Float16 f16x4 __attribute__((ext_vector_type(4)));
typedef float    f32x4 __attribute__((ext_vector_type(4)));

__device__ __forceinline__ int rev4_12(int p) {
  int r = 0;
#pragma unroll
  for (int d = 0; d < 6; ++d) { r = (r << 2) | (p & 3); p >>= 2; }
  return r;
}

// ---------------- filter construction (1 block) ----------------
// Base-4 digit-reversed order, dc_scale and 1/T folded in.
__global__ __launch_bounds__(256) void filter_kernel(
    const float* __restrict__ fm_, const float* __restrict__ bw_,
    const float* __restrict__ sp_, const float* __restrict__ gd_,
    float* __restrict__ filt) {
  __shared__ float smag[F_BINS];
  __shared__ float sred[256];
  const int tid = threadIdx.x;
  for (int f = 0; f < NFILT; ++f) {
    float* Fre = filt + f * 8192;
    float* Fim = Fre + 4096;
    for (int p = tid; p < 4096; p += 256) { Fre[p] = 0.0f; Fim[p] = 0.0f; }
    const float fm = fminf(fmaxf(fm_[f], 1.0f / 128.0f), 45.0f / 128.0f);
    const float bw = fminf(fmaxf(bw_[f], 1.0f / 128.0f), 1.0f);
    const float pp = fminf(fmaxf(sp_[f], 2.0f), 3.0f) * 8.0f - 14.0f;
    const float gd = gd_[f];
    const float scale = bw / (2.0f * powf(0.69314718055994531f, 1.0f / pp));
    float lmax = 0.0f;
    for (int i = tid; i < F_BINS; i += 256) {
      const float n = (float)i / 2048.0f;
      const float m = expf(-powf((fabsf(n - fm) + 1e-8f) / scale, pp));
      smag[i] = m;
      lmax = fmaxf(lmax, m);
    }
    sred[tid] = lmax;
    __syncthreads();
    for (int s = 128; s > 0; s >>= 1) {
      if (tid < s) sred[tid] = fmaxf(sred[tid], sred[tid + s]);
      __syncthreads();
    }
    const float inv = 1.0f / sred[0];
    __syncthreads();
    for (int k = tid; k < F_BINS; k += 256) {
      const float m = smag[k] * inv;
      const float pha = -gd * ((float)k * 0.125f) * PI_F;
      float sn, cs;
      sincosf(pha, &sn, &cs);
      const float dcs = (k == 0) ? 1.0f : 2.0f;
      const float sT = dcs * (1.0f / (float)T_N);
      const int p = rev4_12(k);
      Fre[p] = m * cs * sT;
      Fim[p] = m * sn * sT;
    }
    __syncthreads();
  }
}

// ---------------- radix-4 DIF forward: natural in -> digit-reversed out ------
__device__ __forceinline__ void r4_fwd(float* __restrict__ sre,
                                       float* __restrict__ sim, int tid) {
  for (int m = 1024; m >= 4; m >>= 2) {
    __syncthreads();
    const float astep = -PI_F / (2.0f * (float)m);
#pragma unroll 4
    for (int t = tid; t < 1024; t += 256) {
      const int j = t & (m - 1);
      const int base = ((t - j) << 2) + j;
      const int s0 = SWZ(base), s1 = SWZ(base + m);
      const int s2 = SWZ(base + 2 * m), s3 = SWZ(base + 3 * m);
      float ar = sre[s0], ai = sim[s0];
      float br = sre[s1], bi = sim[s1];
      float cr = sre[s2], ci = sim[s2];
      float dr = sre[s3], di = sim[s3];
      const float t0r = ar + cr, t0i = ai + ci;
      const float t1r = ar - cr, t1i = ai - ci;
      const float t2r = br + dr, t2i = bi + di;
      const float t3r = br - dr, t3i = bi - di;
      const float ang = astep * (float)j;
      const float c1 = __cosf(ang), s1w = __sinf(ang);
      const float c2 = c1 * c1 - s1w * s1w, s2w = 2.0f * c1 * s1w;
      const float c3 = c2 * c1 - s2w * s1w, s3w = c2 * s1w + s2w * c1;
      sre[s0] = t0r + t2r; sim[s0] = t0i + t2i;
      float yr = t1r + t3i, yi = t1i - t3r;              // (t1 - i t3) * W^j
      sre[s1] = yr * c1 - yi * s1w; sim[s1] = yr * s1w + yi * c1;
      yr = t0r - t2r; yi = t0i - t2i;                    // (t0 - t2) * W^2j
      sre[s2] = yr * c2 - yi * s2w; sim[s2] = yr * s2w + yi * c2;
      yr = t1r - t3i; yi = t1i + t3r;                    // (t1 + i t3) * W^3j
      sre[s3] = yr * c3 - yi * s3w; sim[s3] = yr * s3w + yi * c3;
    }
  }
  __syncthreads();                                       // m = 1, W = 1
#pragma unroll 4
  for (int t = tid; t < 1024; t += 256) {
    const int sb = SWZ(t << 2);
    float4 re = *(float4*)&sre[sb];
    float4 im = *(float4*)&sim[sb];
    const float t0r = re.x + re.z, t0i = im.x + im.z;
    const float t1r = re.x - re.z, t1i = im.x - im.z;
    const float t2r = re.y + re.w, t2i = im.y + im.w;
    const float t3r = re.y - re.w, t3i = im.y - im.w;
    re.x = t0r + t2r; im.x = t0i + t2i;
    re.y = t1r + t3i; im.y = t1i - t3r;
    re.z = t0r - t2r; im.z = t0i - t2i;
    re.w = t1r - t3i; im.w = t1i + t3r;
    *(float4*)&sre[sb] = re;
    *(float4*)&sim[sb] = im;
  }
}

// ---------------- radix-4 DIT inverse: digit-reversed in -> natural out ------
__device__ __forceinline__ void r4_inv(float* __restrict__ sre,
                                       float* __restrict__ sim, int tid) {
  __syncthreads();                                       // m = 1, W = 1
#pragma unroll 4
  for (int t = tid; t < 1024; t += 256) {
    const int sb = SWZ(t << 2);
    float4 re = *(float4*)&sre[sb];
    float4 im = *(float4*)&sim[sb];
    const float t0r = re.x + re.z, t0i = im.x + im.z;
    const float t1r = re.x - re.z, t1i = im.x - im.z;
    const float t2r = re.y + re.w, t2i = im.y + im.w;
    const float t3r = re.y - re.w, t3i = im.y - im.w;
    re.x = t0r + t2r; im.x = t0i + t2i;
    re.y = t1r - t3i; im.y = t1i + t3r;
    re.z = t0r - t2r; im.z = t0i - t2i;
    re.w = t1r + t3i; im.w = t1i - t3r;
    *(float4*)&sre[sb] = re;
    *(float4*)&sim[sb] = im;
  }
  for (int m = 4; m <= 1024; m <<= 2) {
    __syncthreads();
    const float astep = PI_F / (2.0f * (float)m);
#pragma unroll 4
    for (int t = tid; t < 1024; t += 256) {
      const int j = t & (m - 1);
      const int base = ((t - j) << 2) + j;
      const int s0 = SWZ(base), s1 = SWZ(base + m);
      const int s2 = SWZ(base + 2 * m), s3 = SWZ(base + 3 * m);
      const float ang = astep * (float)j;
      const float c1 = __cosf(ang), s1w = __sinf(ang);
      const float c2 = c1 * c1 - s1w * s1w, s2w = 2.0f * c1 * s1w;
      const float c3 = c2 * c1 - s2w * s1w, s3w = c2 * s1w + s2w * c1;
      const float b0r = sre[s0], b0i = sim[s0];
      float yr = sre[s1], yi = sim[s1];
      const float b1r = yr * c1 - yi * s1w, b1i = yr * s1w + yi * c1;
      yr = sre[s2]; yi = sim[s2];
      const float b2r = yr * c2 - yi * s2w, b2i = yr * s2w + yi * c2;
      yr = sre[s3]; yi = sim[s3];
      const float b3r = yr * c3 - yi * s3w, b3i = yr * s3w + yi * c3;
      const float t0r = b0r + b2r, t0i = b0i + b2i;
      const float t1r = b0r - b2r, t1i = b0i - b2i;
      const float t2r = b1r + b3r, t2i = b1i + b3i;
      const float t3r = b1r - b3r, t3i = b1i - b3i;
      sre[s0] = t0r + t2r;  sim[s0] = t0i + t2i;
      sre[s1] = t1r - t3i;  sim[s1] = t1i + t3r;
      sre[s2] = t0r - t2r;  sim[s2] = t0i - t2i;
      sre[s3] = t1r + t3i;  sim[s3] = t1i - t3r;
    }
  }
}

// ---------------- forward FFT + filter + inverse FFT + normalize -> f16 ------
__global__ __launch_bounds__(256, 5) void fftfilt_kernel(
    const float* __restrict__ x, const float* __restrict__ filt,
    _Float16* __restrict__ Urg, _Float16* __restrict__ Uig, int chunkbase) {
  const int bb = blockIdx.x >> 6;
  const int c  = blockIdx.x & 63;
  const int b  = chunkbase + bb;
  const int tid = threadIdx.x;
  __shared__ float sre[T_N], sim[T_N];

  const float4* xv = (const float4*)(x + ((size_t)(b * C_N + c)) * T_N);
#pragma unroll
  for (int q = 0; q < 4; ++q) {
    const int i = q * 256 + tid;
    const int sb = SWZ(i * 4);
    *(float4*)&sre[sb] = xv[i];
    *(float4*)&sim[sb] = make_float4(0.f, 0.f, 0.f, 0.f);
  }

  r4_fwd(sre, sim, tid);
  __syncthreads();

  float Xre[16], Xim[16];
#pragma unroll
  for (int q = 0; q < 16; ++q) {
    const int sp = SWZ(q * 256 + tid);
    Xre[q] = sre[sp];
    Xim[q] = sim[sp];
  }
  // no sync needed: each thread only overwrites the slots it itself read

#pragma unroll 1
  for (int f = 0; f < NFILT; ++f) {
    const float* Fre = filt + f * 8192;
    const float* Fim = Fre + 4096;
#pragma unroll
    for (int q = 0; q < 16; ++q) {
      const int p = q * 256 + tid;
      const int sp = SWZ(p);
      sre[sp] = Xre[q] * Fre[p];   // component-wise (digit-rev order)
      sim[sp] = Xim[q] * Fim[p];
    }
    r4_inv(sre, sim, tid);
    __syncthreads();

    const int sl = bb * 2 + f;
    _Float16* upr = Urg + ((size_t)sl * C_N + c) * T_N;
    _Float16* upi = Uig + ((size_t)sl * C_N + c) * T_N;
#pragma unroll
    for (int q = 0; q < 4; ++q) {
      const int idx = q * 1024 + tid * 4;
      const int sb = SWZ(idx);
      const float4 ar = *(float4*)&sre[sb];
      const float4 ai = *(float4*)&sim[sb];
      const float i0 = rsqrtf(ar.x * ar.x + ai.x * ai.x + 1e-6f);
      const float i1 = rsqrtf(ar.y * ar.y + ai.y * ai.y + 1e-6f);
      const float i2 = rsqrtf(ar.z * ar.z + ai.z * ai.z + 1e-6f);
      const float i3 = rsqrtf(ar.w * ar.w + ai.w * ai.w + 1e-6f);
      f16x4 hr, hi;
      hr[0] = (_Float16)(ar.x * i0); hr[1] = (_Float16)(ar.y * i1);
      hr[2] = (_Float16)(ar.z * i2); hr[3] = (_Float16)(ar.w * i3);
      hi[0] = (_Float16)(ai.x * i0); hi[1] = (_Float16)(ai.y * i1);
      hi[2] = (_Float16)(ai.z * i2); hi[3] = (_Float16)(ai.w * i3);
      *(f16x4*)&upr[idx] = hr;
      *(f16x4*)&upi[idx] = hi;
    }
    __syncthreads();
  }
}

// ---------------- gram via f16 MFMA: Rr=UrUr^T, Ii=UiUi^T, Ri=UrUi^T ---------
// ping-pong LDS, 1 barrier per K-step; below-diagonal Rr/Ii tiles skipped
__global__ __launch_bounds__(256) void gram_kernel(
    const _Float16* __restrict__ Urg, const _Float16* __restrict__ Uig,
    float* __restrict__ G, int slicebase) {
  const int sl = blockIdx.x >> 2;           // / TSG
  const int ts = blockIdx.x & (TSG - 1);
  const int tid = threadIdx.x;
  const int w = tid >> 6;
  const int lane = tid & 63;
  __shared__ _Float16 sUr[2][64 * 40], sUi[2][64 * 40];

  const int row = tid >> 2, quarter = tid & 3;
  const size_t goff = (size_t)sl * C_N * T_N + (size_t)row * T_N
                      + ts * (T_N / TSG) + quarter * 8;
  const int loff = row * 40 + quarter * 8;
  const int frow = (lane & 15) * 40 + (lane >> 4) * 8;
  const int aoff = w * 640 + frow;

  f32x4 accRr[4] = {}, accIi[4] = {}, accRi[4] = {};

  f16x8 rr = *(const f16x8*)&Urg[goff];
  f16x8 ri = *(const f16x8*)&Uig[goff];
  int cur = 0;
  for (int ks = 0; ks < NKS; ++ks) {
    *(f16x8*)&sUr[cur][loff] = rr;
    *(f16x8*)&sUi[cur][loff] = ri;
    if (ks + 1 < NKS) {
      rr = *(const f16x8*)&Urg[goff + (ks + 1) * 32];
      ri = *(const f16x8*)&Uig[goff + (ks + 1) * 32];
    }
    __syncthreads();
    const f16x8 ar = *(const f16x8*)&sUr[cur][aoff];
    const f16x8 ai = *(const f16x8*)&sUi[cur][aoff];
#pragma unroll
    for (int n = 0; n < 4; ++n) {
      const f16x8 br = *(const f16x8*)&sUr[cur][n * 640 + frow];
      const f16x8 bi = *(const f16x8*)&sUi[cur][n * 640 + frow];
      accRr[n] = __builtin_amdgcn_mfma_f32_16x16x32_f16(ar, br, accRr[n], 0, 0, 0);
      accIi[n] = __builtin_amdgcn_mfma_f32_16x16x32_f16(ai, bi, accIi[n], 0, 0, 0);
      accRi[n] = __builtin_amdgcn_mfma_f32_16x16x32_f16(ar, bi, accRi[n], 0, 0, 0);
    }
    cur ^= 1;
  }

  float* Gs = G + (size_t)(slicebase + sl) * 12288;
  const int r0 = w * 16 + (lane >> 4) * 4;
  const int c0 = lane & 15;
#pragma unroll
  for (int n = 0; n < 4; ++n) {
    const bool upper = (n >= w);   // skip strictly-below-diagonal Rr/Ii tiles
#pragma unroll
    for (int e = 0; e < 4; ++e) {
      const int idx = (r0 + e) * 64 + n * 16 + c0;
      if (upper) {
        atomicAdd(&Gs[idx], accRr[n][e]);
        atomicAdd(&Gs[4096 + idx], accIi[n][e]);
      }
      atomicAdd(&Gs[8192 + idx], accRi[n][e]);
    }
  }
}

// ---------------- PLV + scatter to feature layout ----------------
__global__ __launch_bounds__(256) void plv_kernel(
    const float* __restrict__ G, float* __restrict__ feats) {
  const int idx = blockIdx.x * 256 + threadIdx.x;
  if (idx >= B_N * NFILT * NPAIRS) return;
  const int slice = idx / NPAIRS;
  const int p = idx - slice * NPAIRS;
  const int b = slice >> 1, f = slice & 1;
  int c = 0, rem = p;
  while (rem >= 63 - c) { rem -= 63 - c; ++c; }
  const int d = c + 1 + rem;
  const float* Gs = G + (size_t)slice * 12288;
  const float cre = Gs[c * 64 + d] + Gs[4096 + c * 64 + d];        // rr + ii
  const float cim = Gs[8192 + c * 64 + d] - Gs[8192 + d * 64 + c]; // ri - ir
  const float plv = sqrtf(cre * cre + cim * cim + 1e-6f) * (1.0f / (float)T_N);
  feats[b * NFEAT + p * NFILT + f] = plv;
}

// ---------------- batch stats (training-mode BN, biased var) ----------------
__global__ __launch_bounds__(256) void stats_kernel(
    const float* __restrict__ feats, float* __restrict__ stats) {
  const int j = blockIdx.x * 256 + threadIdx.x;
  if (j >= NFEAT) return;
  float s = 0.0f;
  for (int b = 0; b < B_N; ++b) s += feats[b * NFEAT + j];
  const float mu = s * (1.0f / (float)B_N);
  float v = 0.0f;
  for (int b = 0; b < B_N; ++b) {
    const float d = feats[b * NFEAT + j] - mu;
    v += d * d;
  }
  v *= (1.0f / (float)B_N);
  stats[j] = mu;
  stats[NFEAT + j] = 1.0f / sqrtf(v + 1e-5f);
}

// ---------------- normalize + linear ----------------
__global__ __launch_bounds__(256) void out_kernel(
    const float* __restrict__ feats, const float* __restrict__ stats,
    const float* __restrict__ w, const float* __restrict__ lb,
    float* __restrict__ out) {
  const int b = blockIdx.x;
  const int tid = threadIdx.x;
  float acc0 = 0, acc1 = 0, acc2 = 0, acc3 = 0;
  for (int j = tid; j < NFEAT; j += 256) {
    const float v = (feats[b * NFEAT + j] - stats[j]) * stats[NFEAT + j];
    acc0 += v * w[0 * NFEAT + j];
    acc1 += v * w[1 * NFEAT + j];
    acc2 += v * w[2 * NFEAT + j];
    acc3 += v * w[3 * NFEAT + j];
  }
  __shared__ float red[4][256];
  red[0][tid] = acc0; red[1][tid] = acc1; red[2][tid] = acc2; red[3][tid] = acc3;
  __syncthreads();
  for (int s = 128; s > 0; s >>= 1) {
    if (tid < s) {
#pragma unroll
      for (int o = 0; o < 4; ++o) red[o][tid] += red[o][tid + s];
    }
    __syncthreads();
  }
  if (tid < 4) out[b * NOUT + tid] = red[tid][0] + lb[tid];
}

extern "C" void kernel_launch(void* const* d_in, const int* in_sizes, int n_in,
                              void* d_out, int out_size, void* d_ws, size_t ws_size,
                              hipStream_t stream) {
  const float* x  = (const float*)d_in[0];
  const float* fm = (const float*)d_in[1];
  const float* bw = (const float*)d_in[2];
  const float* sp = (const float*)d_in[3];
  const float* gd = (const float*)d_in[4];
  const float* lw = (const float*)d_in[5];
  const float* lb = (const float*)d_in[6];
  float* out = (float*)d_out;
  char* base = (char*)d_ws;

  // adaptive batch chunk: largest of {64,32,16} whose u-buffer fits ws
  const size_t fixed = 65536 + 6291456 + (size_t)B_N * NFEAT * 4 + 2 * NFEAT * 4;
  int CB = 64;
  if (ws_size < fixed + (size_t)64 * 2097152) CB = 32;
  if (ws_size < fixed + (size_t)32 * 2097152) CB = 16;
  const int nchunk = B_N / CB;

  const size_t u_bytes = (size_t)CB * 1048576;  // per component array
  float*    filt  = (float*)base;
  _Float16* Urg   = (_Float16*)(base + 65536);
  _Float16* Uig   = (_Float16*)(base + 65536 + u_bytes);
  float*    G     = (float*)(base + 65536 + 2 * u_bytes);
  float*    feats = (float*)(base + 65536 + 2 * u_bytes + 6291456);
  float*    stats = feats + (size_t)B_N * NFEAT;

  hipMemsetAsync(G, 0, 6291456, stream);
  filter_kernel<<<1, 256, 0, stream>>>(fm, bw, sp, gd, filt);

  for (int chunk = 0; chunk < nchunk; ++chunk) {
    fftfilt_kernel<<<CB * C_N, 256, 0, stream>>>(x, filt, Urg, Uig, chunk * CB);
    gram_kernel<<<CB * 2 * TSG, 256, 0, stream>>>(Urg, Uig, G, chunk * CB * 2);
  }

  plv_kernel<<<(B_N * NFILT * NPAIRS + 255) / 256, 256, 0, stream>>>(G, feats);
  stats_kernel<<<(NFEAT + 255) / 256, 256, 0, stream>>>(feats, stats);
  out_kernel<<<B_N, 256, 0, stream>>>(feats, stats, lw, lb, out);
}